// Round 1
// baseline (548.599 us; speedup 1.0000x reference)
//
#include <hip/hip_runtime.h>

#define NODES   50000
#define EDGES   1200000
#define IND     256
#define HID     64
#define BN_EPS  1e-5f

// ---------------------------------------------------------------- init / degree
__global__ __launch_bounds__(256) void k_init(int* degi, float* bnsum, float* bnsq) {
    int t = blockIdx.x * 256 + threadIdx.x;
    if (t < NODES) degi[t] = 1;              // self-loop
    if (t < HID) { bnsum[t] = 0.f; bnsq[t] = 0.f; }
}

__global__ __launch_bounds__(256) void k_deg(const int* __restrict__ dst, int* degi) {
    int e = blockIdx.x * 256 + threadIdx.x;
    if (e < EDGES) atomicAdd(&degi[dst[e]], 1);
}

__global__ __launch_bounds__(256) void k_dinv(const int* __restrict__ degi, float* dinv) {
    int n = blockIdx.x * 256 + threadIdx.x;
    if (n < NODES) dinv[n] = rsqrtf((float)degi[n]);
}

// ---------------------------------------------------------------- GEMM1: g = (x @ W1) * dinv, acc = g
__global__ __launch_bounds__(256) void k_gemm1(const float* __restrict__ x, const float* __restrict__ W1,
                                               const float* __restrict__ dinv,
                                               float* __restrict__ g, float* __restrict__ acc) {
    __shared__ float sW[IND * HID];   // 64 KB
    __shared__ float sX[16 * IND];    // 16 KB
    int t = threadIdx.x;

    const float4* W4 = (const float4*)W1;
    float4* sW4 = (float4*)sW;
#pragma unroll
    for (int i = 0; i < 16; ++i) sW4[t + 256 * i] = W4[t + 256 * i];

    int base = blockIdx.x * 16;
    const float4* x4 = (const float4*)(x + base * IND);
    float4* sX4 = (float4*)sX;
#pragma unroll
    for (int i = 0; i < 4; ++i) sX4[t + 256 * i] = x4[t + 256 * i];
    __syncthreads();

    int j = t & 63;
    int r0 = (t >> 6) * 4;   // this thread's 4 rows: r0..r0+3
    float s0 = 0.f, s1 = 0.f, s2 = 0.f, s3 = 0.f;
    for (int k = 0; k < IND; k += 4) {
        float w0 = sW[(k + 0) * HID + j];
        float w1 = sW[(k + 1) * HID + j];
        float w2 = sW[(k + 2) * HID + j];
        float w3 = sW[(k + 3) * HID + j];
        float4 a0 = *(const float4*)&sX[(r0 + 0) * IND + k];
        float4 a1 = *(const float4*)&sX[(r0 + 1) * IND + k];
        float4 a2 = *(const float4*)&sX[(r0 + 2) * IND + k];
        float4 a3 = *(const float4*)&sX[(r0 + 3) * IND + k];
        s0 += a0.x * w0 + a0.y * w1 + a0.z * w2 + a0.w * w3;
        s1 += a1.x * w0 + a1.y * w1 + a1.z * w2 + a1.w * w3;
        s2 += a2.x * w0 + a2.y * w1 + a2.z * w2 + a2.w * w3;
        s3 += a3.x * w0 + a3.y * w1 + a3.z * w2 + a3.w * w3;
    }
    float r[4] = { s0, s1, s2, s3 };
#pragma unroll
    for (int i = 0; i < 4; ++i) {
        int n = base + r0 + i;
        float v = r[i] * dinv[n];
        g[n * HID + j] = v;
        acc[n * HID + j] = v;
    }
}

// ---------------------------------------------------------------- conv1 scatter: wave per edge, lane = dim
__global__ __launch_bounds__(256) void k_scatter1(const int* __restrict__ src, const int* __restrict__ dst,
                                                  const float* __restrict__ g, float* acc) {
    int gt = blockIdx.x * 256 + threadIdx.x;
    int e = gt >> 6;
    int lane = threadIdx.x & 63;
    if (e < EDGES) {
        int s = src[e];
        int d = dst[e];
        atomicAdd(&acc[d * HID + lane], g[s * HID + lane]);
    }
}

// ---------------------------------------------------------------- BN stats: h1 = acc*dinv + b1; column sums
__global__ __launch_bounds__(256) void k_bnstats(const float* __restrict__ acc, const float* __restrict__ dinv,
                                                 const float* __restrict__ b1, float* __restrict__ h1,
                                                 float* bnsum, float* bnsq) {
    __shared__ float sS[256], sQ[256];
    int t = threadIdx.x;
    int j = t & 63;
    int worker = (blockIdx.x * 256 + t) >> 6;
    int nworkers = (gridDim.x * 256) >> 6;
    float b = b1[j];
    float s = 0.f, q = 0.f;
    for (int n = worker; n < NODES; n += nworkers) {
        float v = fmaf(acc[n * HID + j], dinv[n], b);
        h1[n * HID + j] = v;
        s += v;
        q += v * v;
    }
    sS[t] = s; sQ[t] = q;
    __syncthreads();
    if (t < 64) {
        s = sS[t] + sS[t + 64] + sS[t + 128] + sS[t + 192];
        q = sQ[t] + sQ[t + 64] + sQ[t + 128] + sQ[t + 192];
        atomicAdd(&bnsum[t], s);
        atomicAdd(&bnsq[t], q);
    }
}

__global__ void k_bnfinal(const float* bnsum, const float* bnsq, const float* gamma, const float* beta,
                          float* scale, float* shift) {
    int j = threadIdx.x;
    if (j < HID) {
        float mean = bnsum[j] * (1.f / NODES);
        float var  = bnsq[j] * (1.f / NODES) - mean * mean;
        float sc = gamma[j] * rsqrtf(var + BN_EPS);
        scale[j] = sc;
        shift[j] = beta[j] - mean * sc;
    }
}

// ---------------------------------------------------------------- q = relu(bn(h1)) @ W2 * dinv ; acc2 = q
__global__ __launch_bounds__(256) void k_q(const float* __restrict__ h1, const float* __restrict__ scale,
                                           const float* __restrict__ shift, const float* __restrict__ W2,
                                           const float* __restrict__ dinv, float* q, float* acc2) {
    int gt = blockIdx.x * 256 + threadIdx.x;
    int lane = threadIdx.x & 63;
    int n = gt >> 6;
    if (n >= NODES) return;
    float v = fmaxf(fmaf(h1[n * HID + lane], scale[lane], shift[lane]), 0.f);
    float q0 = v * W2[lane * 2 + 0];
    float q1 = v * W2[lane * 2 + 1];
#pragma unroll
    for (int off = 32; off; off >>= 1) {
        q0 += __shfl_down(q0, off);
        q1 += __shfl_down(q1, off);
    }
    if (lane == 0) {
        float di = dinv[n];
        q0 *= di; q1 *= di;
        q[n * 2 + 0] = q0;  q[n * 2 + 1] = q1;
        acc2[n * 2 + 0] = q0; acc2[n * 2 + 1] = q1;
    }
}

// ---------------------------------------------------------------- conv2 scatter: thread per edge
__global__ __launch_bounds__(256) void k_scatter2(const int* __restrict__ src, const int* __restrict__ dst,
                                                  const float* __restrict__ q, float* acc2) {
    int e = blockIdx.x * 256 + threadIdx.x;
    if (e < EDGES) {
        int s = src[e];
        int d = dst[e];
        atomicAdd(&acc2[d * 2 + 0], q[s * 2 + 0]);
        atomicAdd(&acc2[d * 2 + 1], q[s * 2 + 1]);
    }
}

// ---------------------------------------------------------------- epilogue
__global__ __launch_bounds__(256) void k_final(const float* __restrict__ acc2, const float* __restrict__ dinv,
                                               const float* __restrict__ b2, float* out) {
    int i = blockIdx.x * 256 + threadIdx.x;
    if (i < NODES * 2) {
        out[i] = fmaf(acc2[i], dinv[i >> 1], b2[i & 1]);
    }
}

extern "C" void kernel_launch(void* const* d_in, const int* in_sizes, int n_in,
                              void* d_out, int out_size, void* d_ws, size_t ws_size,
                              hipStream_t stream) {
    const float* x     = (const float*)d_in[0];
    const int*   ei    = (const int*)d_in[1];
    const float* W1    = (const float*)d_in[2];
    const float* b1    = (const float*)d_in[3];
    const float* gamma = (const float*)d_in[4];
    const float* beta  = (const float*)d_in[5];
    const float* W2    = (const float*)d_in[6];
    const float* b2    = (const float*)d_in[7];
    const int* src = ei;
    const int* dst = ei + EDGES;
    float* out = (float*)d_out;

    float* f     = (float*)d_ws;
    float* dinv  = f;                         // 50048 (padded)
    float* g     = dinv + 50048;              // NODES*HID
    float* acc   = g + NODES * HID;           // NODES*HID
    float* q     = acc + NODES * HID;         // NODES*2
    float* acc2  = q + NODES * 2;             // NODES*2
    float* bnsum = acc2 + NODES * 2;          // 64
    float* bnsq  = bnsum + 64;                // 64
    float* scale = bnsq + 64;                 // 64
    float* shift = scale + 64;                // 64
    int*   degi  = (int*)(shift + 64);        // NODES

    k_init<<<(NODES + 255) / 256, 256, 0, stream>>>(degi, bnsum, bnsq);
    k_deg<<<(EDGES + 255) / 256, 256, 0, stream>>>(dst, degi);
    k_dinv<<<(NODES + 255) / 256, 256, 0, stream>>>(degi, dinv);
    k_gemm1<<<NODES / 16, 256, 0, stream>>>(x, W1, dinv, g, acc);
    k_scatter1<<<(EDGES * 64) / 256, 256, 0, stream>>>(src, dst, g, acc);
    k_bnstats<<<256, 256, 0, stream>>>(acc, dinv, b1, g, bnsum, bnsq);
    k_bnfinal<<<1, 64, 0, stream>>>(bnsum, bnsq, gamma, beta, scale, shift);
    k_q<<<(NODES * 64) / 256, 256, 0, stream>>>(g, scale, shift, W2, dinv, q, acc2);
    k_scatter2<<<(EDGES + 255) / 256, 256, 0, stream>>>(src, dst, q, acc2);
    k_final<<<(NODES * 2 + 255) / 256, 256, 0, stream>>>(acc2, dinv, b2, out);
}

// Round 2
// 333.616 us; speedup vs baseline: 1.6444x; 1.6444x over previous
//
#include <hip/hip_runtime.h>

#define NODES   50000
#define EDGES   1200000
#define IND     256
#define HID     64
#define BN_EPS  1e-5f
#define NB_SCAN 196   // ceil(50000/256)

// ---------------------------------------------------------------- init
__global__ __launch_bounds__(256) void k_init(int* degi, float* bnsum, float* bnsq) {
    int t = blockIdx.x * 256 + threadIdx.x;
    if (t < NODES) degi[t] = 0;              // edge-only in-degree (self-loop added in dinv)
    if (t < HID) { bnsum[t] = 0.f; bnsq[t] = 0.f; }
}

__global__ __launch_bounds__(256) void k_deg(const int* __restrict__ dst, int* degi) {
    int e = blockIdx.x * 256 + threadIdx.x;
    if (e < EDGES) atomicAdd(&degi[dst[e]], 1);
}

__global__ __launch_bounds__(256) void k_dinv(const int* __restrict__ degi, float* dinv) {
    int n = blockIdx.x * 256 + threadIdx.x;
    if (n < NODES) dinv[n] = rsqrtf((float)(degi[n] + 1));
}

// ---------------------------------------------------------------- scan (3-phase)
__global__ __launch_bounds__(256) void k_scan1(const int* __restrict__ degi, int* part, int* bsum) {
    __shared__ int s[256];
    int t = threadIdx.x;
    int i = blockIdx.x * 256 + t;
    int v = (i < NODES) ? degi[i] : 0;
    s[t] = v;
    __syncthreads();
    for (int off = 1; off < 256; off <<= 1) {
        int a = (t >= off) ? s[t - off] : 0;
        __syncthreads();
        s[t] += a;
        __syncthreads();
    }
    if (i < NODES) part[i] = s[t] - v;        // exclusive within block
    if (t == 255) bsum[blockIdx.x] = s[t];    // block total
}

__global__ __launch_bounds__(256) void k_scan2(const int* __restrict__ bsum, int* bbase) {
    __shared__ int s[256];
    int t = threadIdx.x;
    int v = (t < NB_SCAN) ? bsum[t] : 0;
    s[t] = v;
    __syncthreads();
    for (int off = 1; off < 256; off <<= 1) {
        int a = (t >= off) ? s[t - off] : 0;
        __syncthreads();
        s[t] += a;
        __syncthreads();
    }
    bbase[t] = s[t] - v;                      // exclusive across blocks
}

__global__ __launch_bounds__(256) void k_scan3(const int* __restrict__ part, const int* __restrict__ bbase,
                                               int* offsets, int* cursor) {
    int i = blockIdx.x * 256 + threadIdx.x;
    if (i < NODES) {
        int o = part[i] + bbase[i >> 8];
        offsets[i] = o;
        cursor[i] = o;
    }
    if (i == 0) offsets[NODES] = EDGES;
}

__global__ __launch_bounds__(256) void k_fill(const int* __restrict__ src, const int* __restrict__ dst,
                                              int* cursor, int* csr_src) {
    int e = blockIdx.x * 256 + threadIdx.x;
    if (e < EDGES) {
        int d = dst[e];
        int pos = atomicAdd(&cursor[d], 1);
        csr_src[pos] = src[e];
    }
}

// ---------------------------------------------------------------- GEMM1: g = (x @ W1) * dinv
__global__ __launch_bounds__(256) void k_gemm1(const float* __restrict__ x, const float* __restrict__ W1,
                                               const float* __restrict__ dinv, float* __restrict__ g) {
    __shared__ float sW[IND * HID];   // 64 KB
    __shared__ float sX[16 * IND];    // 16 KB
    int t = threadIdx.x;

    const float4* W4 = (const float4*)W1;
    float4* sW4 = (float4*)sW;
#pragma unroll
    for (int i = 0; i < 16; ++i) sW4[t + 256 * i] = W4[t + 256 * i];

    int base = blockIdx.x * 16;
    const float4* x4 = (const float4*)(x + base * IND);
    float4* sX4 = (float4*)sX;
#pragma unroll
    for (int i = 0; i < 4; ++i) sX4[t + 256 * i] = x4[t + 256 * i];
    __syncthreads();

    int j = t & 63;
    int r0 = (t >> 6) * 4;
    float s0 = 0.f, s1 = 0.f, s2 = 0.f, s3 = 0.f;
    for (int k = 0; k < IND; k += 4) {
        float w0 = sW[(k + 0) * HID + j];
        float w1 = sW[(k + 1) * HID + j];
        float w2 = sW[(k + 2) * HID + j];
        float w3 = sW[(k + 3) * HID + j];
        float4 a0 = *(const float4*)&sX[(r0 + 0) * IND + k];
        float4 a1 = *(const float4*)&sX[(r0 + 1) * IND + k];
        float4 a2 = *(const float4*)&sX[(r0 + 2) * IND + k];
        float4 a3 = *(const float4*)&sX[(r0 + 3) * IND + k];
        s0 += a0.x * w0 + a0.y * w1 + a0.z * w2 + a0.w * w3;
        s1 += a1.x * w0 + a1.y * w1 + a1.z * w2 + a1.w * w3;
        s2 += a2.x * w0 + a2.y * w1 + a2.z * w2 + a2.w * w3;
        s3 += a3.x * w0 + a3.y * w1 + a3.z * w2 + a3.w * w3;
    }
    float r[4] = { s0, s1, s2, s3 };
#pragma unroll
    for (int i = 0; i < 4; ++i) {
        int n = base + r0 + i;
        g[n * HID + j] = r[i] * dinv[n];
    }
}

// ---------------------------------------------------------------- conv1 gather: wave per node, lane = dim
__global__ __launch_bounds__(256) void k_gather1(const int* __restrict__ offsets, const int* __restrict__ csr_src,
                                                 const float* __restrict__ g, const float* __restrict__ dinv,
                                                 const float* __restrict__ b1, float* __restrict__ h1) {
    int n = (blockIdx.x * 256 + threadIdx.x) >> 6;
    int lane = threadIdx.x & 63;
    if (n >= NODES) return;
    float v = g[n * HID + lane];             // self-loop term
    int beg = offsets[n], end = offsets[n + 1];
    for (int b = beg; b < end; b += 64) {
        int cnt = end - b; if (cnt > 64) cnt = 64;
        int sidx = 0;
        if (b + lane < end) sidx = csr_src[b + lane];
        for (int k = 0; k < cnt; ++k) {
            int s = __shfl(sidx, k);
            v += g[s * HID + lane];
        }
    }
    h1[n * HID + lane] = fmaf(v, dinv[n], b1[lane]);
}

// ---------------------------------------------------------------- BN stats over h1
__global__ __launch_bounds__(256) void k_bnstats(const float* __restrict__ h1, float* bnsum, float* bnsq) {
    __shared__ float sS[256], sQ[256];
    int t = threadIdx.x;
    int j = t & 63;
    int worker = (blockIdx.x * 256 + t) >> 6;
    int nworkers = (gridDim.x * 256) >> 6;
    float s = 0.f, q = 0.f;
    for (int n = worker; n < NODES; n += nworkers) {
        float v = h1[n * HID + j];
        s += v;
        q += v * v;
    }
    sS[t] = s; sQ[t] = q;
    __syncthreads();
    if (t < 64) {
        s = sS[t] + sS[t + 64] + sS[t + 128] + sS[t + 192];
        q = sQ[t] + sQ[t + 64] + sQ[t + 128] + sQ[t + 192];
        atomicAdd(&bnsum[t], s);
        atomicAdd(&bnsq[t], q);
    }
}

__global__ void k_bnfinal(const float* bnsum, const float* bnsq, const float* gamma, const float* beta,
                          float* scale, float* shift) {
    int j = threadIdx.x;
    if (j < HID) {
        float mean = bnsum[j] * (1.f / NODES);
        float var  = bnsq[j] * (1.f / NODES) - mean * mean;
        float sc = gamma[j] * rsqrtf(var + BN_EPS);
        scale[j] = sc;
        shift[j] = beta[j] - mean * sc;
    }
}

// ---------------------------------------------------------------- q = relu(bn(h1)) @ W2 * dinv
__global__ __launch_bounds__(256) void k_q(const float* __restrict__ h1, const float* __restrict__ scale,
                                           const float* __restrict__ shift, const float* __restrict__ W2,
                                           const float* __restrict__ dinv, float* q) {
    int gt = blockIdx.x * 256 + threadIdx.x;
    int lane = threadIdx.x & 63;
    int n = gt >> 6;
    if (n >= NODES) return;
    float v = fmaxf(fmaf(h1[n * HID + lane], scale[lane], shift[lane]), 0.f);
    float q0 = v * W2[lane * 2 + 0];
    float q1 = v * W2[lane * 2 + 1];
#pragma unroll
    for (int off = 32; off; off >>= 1) {
        q0 += __shfl_down(q0, off);
        q1 += __shfl_down(q1, off);
    }
    if (lane == 0) {
        float di = dinv[n];
        q[n * 2 + 0] = q0 * di;
        q[n * 2 + 1] = q1 * di;
    }
}

// ---------------------------------------------------------------- conv2 gather: 4 lanes per node
__global__ __launch_bounds__(256) void k_gather2(const int* __restrict__ offsets, const int* __restrict__ csr_src,
                                                 const float* __restrict__ q, const float* __restrict__ dinv,
                                                 const float* __restrict__ b2, float* __restrict__ out) {
    int gt = blockIdx.x * 256 + threadIdx.x;
    int n = gt >> 2;
    int sub = gt & 3;
    if (n >= NODES) return;
    const float2* q2 = (const float2*)q;
    float q0 = 0.f, q1 = 0.f;
    if (sub == 0) { float2 s = q2[n]; q0 = s.x; q1 = s.y; }   // self-loop
    int beg = offsets[n], end = offsets[n + 1];
    for (int e = beg + sub; e < end; e += 4) {
        float2 m = q2[csr_src[e]];
        q0 += m.x; q1 += m.y;
    }
    q0 += __shfl_xor(q0, 1); q1 += __shfl_xor(q1, 1);
    q0 += __shfl_xor(q0, 2); q1 += __shfl_xor(q1, 2);
    if (sub == 0) {
        float di = dinv[n];
        out[n * 2 + 0] = fmaf(q0, di, b2[0]);
        out[n * 2 + 1] = fmaf(q1, di, b2[1]);
    }
}

extern "C" void kernel_launch(void* const* d_in, const int* in_sizes, int n_in,
                              void* d_out, int out_size, void* d_ws, size_t ws_size,
                              hipStream_t stream) {
    const float* x     = (const float*)d_in[0];
    const int*   ei    = (const int*)d_in[1];
    const float* W1    = (const float*)d_in[2];
    const float* b1    = (const float*)d_in[3];
    const float* gamma = (const float*)d_in[4];
    const float* beta  = (const float*)d_in[5];
    const float* W2    = (const float*)d_in[6];
    const float* b2    = (const float*)d_in[7];
    const int* src = ei;
    const int* dst = ei + EDGES;
    float* out = (float*)d_out;

    float* f     = (float*)d_ws;
    float* dinv  = f;                          // 50048
    float* g     = dinv + 50048;               // NODES*HID
    float* h1    = g + NODES * HID;            // NODES*HID
    float* q     = h1 + NODES * HID;           // NODES*2
    float* bnsum = q + NODES * 2;              // 64
    float* bnsq  = bnsum + 64;                 // 64
    float* scale = bnsq + 64;                  // 64
    float* shift = scale + 64;                 // 64
    int*   degi    = (int*)(shift + 64);       // 50000
    int*   part    = degi + 50000;             // 50176
    int*   bsum    = part + 50176;             // 256
    int*   bbase   = bsum + 256;               // 256
    int*   offsets = bbase + 256;              // 50001 (+pad)
    int*   cursor  = offsets + 50052;          // 50000
    int*   csr_src = cursor + 50000;           // EDGES

    k_init <<<(NODES + 255) / 256, 256, 0, stream>>>(degi, bnsum, bnsq);
    k_deg  <<<(EDGES + 255) / 256, 256, 0, stream>>>(dst, degi);
    k_dinv <<<(NODES + 255) / 256, 256, 0, stream>>>(degi, dinv);
    k_scan1<<<NB_SCAN, 256, 0, stream>>>(degi, part, bsum);
    k_scan2<<<1, 256, 0, stream>>>(bsum, bbase);
    k_scan3<<<NB_SCAN, 256, 0, stream>>>(part, bbase, offsets, cursor);
    k_fill <<<(EDGES + 255) / 256, 256, 0, stream>>>(src, dst, cursor, csr_src);
    k_gemm1<<<NODES / 16, 256, 0, stream>>>(x, W1, dinv, g);
    k_gather1<<<(NODES * 64 + 255) / 256, 256, 0, stream>>>(offsets, csr_src, g, dinv, b1, h1);
    k_bnstats<<<256, 256, 0, stream>>>(h1, bnsum, bnsq);
    k_bnfinal<<<1, 64, 0, stream>>>(bnsum, bnsq, gamma, beta, scale, shift);
    k_q<<<(NODES * 64 + 255) / 256, 256, 0, stream>>>(h1, scale, shift, W2, dinv, q);
    k_gather2<<<(NODES * 4 + 255) / 256, 256, 0, stream>>>(offsets, csr_src, q, dinv, b2, out);
}